// Round 10
// baseline (71.910 us; speedup 1.0000x reference)
//
#include <hip/hip_runtime.h>
#include <math.h>

#define B_   16
#define D_   512
#define T_   4096
#define CD   10
#define CS   1024
#define NTOK (B_*T_)              // 65536
#define TPB_A 128                 // tokens per block, fused kernel
#define NBLK_A (NTOK/TPB_A)       // 512

typedef float f32x2 __attribute__((ext_vector_type(2)));
typedef float f32x4 __attribute__((ext_vector_type(4)));

// ws layout (float offsets)
#define WS_WT     0               // 5120  (w_t[D][d], transposed, normalized)
#define WS_WNP    5120            // 8192  (wnp[D][16]: 10 wn + ob + pad)
#define WS_PARTH  13312           // 1024
#define WS_PARTC  14336           // 1024
#define WS_CNT    15360           // 1 (int ticket counter)
#define WS_HIST   15616           // 512*1024 = 524288
#define WS_HMID   539904          // 32*1024

// --------------------------------------------- prep: w_t + wnp tables
// blocks 0..9: transposed normalized in-weights (validated R3/R7 op order).
// blocks 10,11: packed normalized out-weights wnp[D][16] (validated
// build_table/R7-staging op order: s2 ascending, sc=g/sqrtf(s2), w=vv*sc).
__global__ __launch_bounds__(256) void prep_wt(
    const float* __restrict__ in_v, const float* __restrict__ in_g,
    const float* __restrict__ out_v, const float* __restrict__ out_g,
    const float* __restrict__ out_b,
    float* __restrict__ w_t, float* __restrict__ wnp,
    int* __restrict__ counter)
{
  const int blk = blockIdx.x;
  const int tid = threadIdx.x;
  if (blk < 10) {
    __shared__ double pn[16];
    __shared__ float nrm_s;
    const int d = blk;
    if (d == 0 && tid == 0) *counter = 0;   // reset cooperative ticket
    if (tid < 16) {
      double s = 0.0;
      const float* vp = in_v + d*D_ + tid*32;
      #pragma unroll
      for (int k = 0; k < 32; ++k) { double v = (double)vp[k]; s += v*v; }
      pn[tid] = s;
    }
    __syncthreads();
    if (tid == 0) {
      double s = 0.0;
      #pragma unroll
      for (int j = 0; j < 16; ++j) s += pn[j];
      nrm_s = (float)sqrt(s);
    }
    __syncthreads();
    const float g = in_g[d], nrm = nrm_s;
    for (int D = tid; D < D_; D += 256)
      w_t[D*CD + d] = g * in_v[d*D_ + D] / nrm;
  } else {
    const int D = (blk - 10) * 256 + tid;
    const float* vr = out_v + D*CD;
    float vv[CD];
    float s2 = 0.f;
    #pragma unroll
    for (int d = 0; d < CD; ++d) { vv[d] = vr[d]; s2 += vv[d]*vv[d]; }
    const float sc = out_g[D] / sqrtf(s2);
    #pragma unroll
    for (int d = 0; d < CD; ++d) wnp[D*16 + d] = vv[d] * sc;
    wnp[D*16 + 10] = out_b[D];
  }
}

// ------------------------------------- fused: in-proj + stats + out-proj
// Phase A/B identical to validated R7/R9. Phase C: weights via wave-uniform
// scalar loads from wnp (SMEM pipe), D wave-uniform, f32x2 NT stores.
__global__ __launch_bounds__(256) void lfq_fused(
    const float* __restrict__ x, const float* __restrict__ in_b,
    const float* __restrict__ w_t, const float* __restrict__ wnp,
    float* __restrict__ out, float* __restrict__ out_idx,
    float* __restrict__ partH, float* __restrict__ partC,
    float* __restrict__ hist_part)
{
  __shared__ float  hist[CS];            // 4 KB
  __shared__ int    sidx[TPB_A];         // 512 B
  __shared__ double red[4*TPB_A*CD];     // 40 KB

  const int tid  = threadIdx.x;
  const int blk  = blockIdx.x;
  const int b    = blk >> 5;
  const int t0   = (blk & 31) * TPB_A;
  const int wave = __builtin_amdgcn_readfirstlane(tid >> 6);
  const int lane = tid & 63;

  for (int i = tid; i < CS; i += 256) hist[i] = 0.f;

  // phase A: f64 in-proj. wave = 128-D slice, lane = 2 tokens (float2).
  // weight addresses wave-uniform -> scalar (SMEM) loads.
  double acc[2*CD];
  #pragma unroll
  for (int i = 0; i < 2*CD; ++i) acc[i] = 0.0;
  const float* xb = x + ((size_t)b * D_ + wave * 128) * T_ + t0 + 2*lane;
  const float* wp = w_t + (size_t)wave * 128 * CD;
  #pragma unroll 8
  for (int Di = 0; Di < 128; ++Di) {
    f32x2 xv = *(const f32x2*)(xb + (size_t)Di * T_);
    double x0 = (double)xv.x, x1 = (double)xv.y;
    const f32x2* w2 = (const f32x2*)(wp + Di * CD);
    #pragma unroll
    for (int i = 0; i < 5; ++i) {
      f32x2 w = w2[i];
      acc[4*i+0] += (double)w.x * x0;
      acc[4*i+1] += (double)w.x * x1;
      acc[4*i+2] += (double)w.y * x0;
      acc[4*i+3] += (double)w.y * x1;
    }
  }
  #pragma unroll
  for (int d = 0; d < CD; ++d) {
    red[((size_t)wave*TPB_A + 2*lane + 0)*CD + d] = acc[2*d+0];
    red[((size_t)wave*TPB_A + 2*lane + 1)*CD + d] = acc[2*d+1];
  }
  __syncthreads();

  // phase B: waves 0,1 -> quantize / entropy / histogram (waves 2,3 idle)
  if (wave < 2) {
    const int ti = wave*64 + lane;
    float Hs = 0.f, C = 0.f;
    int   idx = 0;
    int   k = 0; int pos[CD]; float ms[CD];
    #pragma unroll
    for (int d = 0; d < CD; ++d) {
      double o = red[(size_t)(0*TPB_A + ti)*CD + d]
               + red[(size_t)(1*TPB_A + ti)*CD + d]
               + red[(size_t)(2*TPB_A + ti)*CD + d]
               + red[(size_t)(3*TPB_A + ti)*CD + d]
               + (double)in_b[d];
      float v = (float)o;
      int bit = (v > 0.f);
      idx |= bit << (9 - d);
      float c = v - (bit ? 1.f : -1.f);
      C += c * c;
      float e = __expf(-400.f * fabsf(v));   // exp(-|delta logit|)
      if (e > 1e-9f) { ms[k] = e / (1.f + e); pos[k] = 9 - d; ++k; }
    }
    int nc = 1 << k;
    for (int c = 0; c < nc; ++c) {
      float p = 1.f; int bin = idx;
      for (int i = 0; i < k; ++i) {
        if ((c >> i) & 1) { p *= ms[i]; bin ^= (1 << pos[i]); }
        else              { p *= (1.f - ms[i]); }
      }
      Hs -= p * __logf(fmaxf(p, 1e-5f));
      atomicAdd(&hist[bin], p);
    }
    out_idx[b * T_ + t0 + ti] = (float)idx;
    sidx[ti] = idx;
    #pragma unroll
    for (int off = 32; off > 0; off >>= 1) {
      Hs += __shfl_down(Hs, off, 64);
      C  += __shfl_down(C,  off, 64);
    }
    if (lane == 0) { partH[blk*2 + wave] = Hs; partC[blk*2 + wave] = C; }
  }
  __syncthreads();

  for (int i = tid; i < CS; i += 256) hist_part[(size_t)blk*CS + i] = hist[i];

  // phase C: direct out-projection. D wave-uniform (SMEM weight loads),
  // lane covers 2 adjacent tokens; ascending +-w adds from ob (R7 order).
  const int c0 = sidx[2*lane + 0], c1 = sidx[2*lane + 1];
  float* op = out + ((size_t)b * D_) * T_ + t0 + 2*lane;
  #pragma unroll 4
  for (int it = 0; it < 128; ++it) {
    const int D = wave + it*4;               // wave-uniform
    const float* wr = wnp + D*16;            // -> s_load
    float s0 = wr[10], s1 = wr[10];          // ob
    #pragma unroll
    for (int d = 0; d < CD; ++d) {
      const float w = wr[d];
      const int sh = 9 - d;
      s0 += ((c0 >> sh) & 1) ? w : -w;
      s1 += ((c1 >> sh) & 1) ? w : -w;
    }
    f32x2 o; o.x = s0; o.y = s1;
    __builtin_nontemporal_store(o, (f32x2*)(op + (size_t)D * T_));
  }
}

// --------------------------- tail: hist reduce + finalize (cooperative)
// Validated in R6/R7/R9.
__global__ __launch_bounds__(256) void hist_final(
    const float* __restrict__ hist_part, const float* __restrict__ partH,
    const float* __restrict__ partC, float* __restrict__ hmid,
    int* __restrict__ counter, float* __restrict__ aux_out)
{
  const int r   = blockIdx.x;          // 0..31
  const int tid = threadIdx.x;
  #pragma unroll
  for (int q = 0; q < 4; ++q) {
    const int bin = q*256 + tid;
    float s = 0.f;
    for (int m = 0; m < 16; ++m)
      s += hist_part[(size_t)(r*16 + m)*CS + bin];
    hmid[r*CS + bin] = s;
  }
  __threadfence();
  __shared__ int ticket_s;
  if (tid == 0) ticket_s = atomicAdd(counter, 1);
  __syncthreads();
  if (ticket_s != 31) return;          // not the last block
  __threadfence();                     // acquire: others' hmid now visible

  float ce = 0.f, h = 0.f, cm = 0.f;
  #pragma unroll
  for (int q = 0; q < 4; ++q) {
    const int bin = q*256 + tid;
    float s = 0.f;
    for (int rr = 0; rr < 32; ++rr) s += hmid[rr*CS + bin];
    float ap = s * (1.f/65536.f);
    ce += -ap * __logf(fmaxf(ap, 1e-5f));
  }
  for (int i = tid; i < 1024; i += 256) { h += partH[i]; cm += partC[i]; }
  __shared__ float rb[3][256];
  rb[0][tid] = ce; rb[1][tid] = h; rb[2][tid] = cm;
  __syncthreads();
  for (int s = 128; s > 0; s >>= 1) {
    if (tid < s) {
      rb[0][tid] += rb[0][tid+s];
      rb[1][tid] += rb[1][tid+s];
      rb[2][tid] += rb[2][tid+s];
    }
    __syncthreads();
  }
  if (tid == 0) {
    float psH    = rb[1][0] * (1.f/65536.f);
    float commit = rb[2][0] * (1.f/655360.f);
    aux_out[0] = psH - rb[0][0] + commit;
  }
}

// ---------------------------------------------------------------- launch
extern "C" void kernel_launch(void* const* d_in, const int* in_sizes, int n_in,
                              void* d_out, int out_size, void* d_ws, size_t ws_size,
                              hipStream_t stream) {
  const float* x     = (const float*)d_in[0];
  const float* in_v  = (const float*)d_in[1];
  const float* in_g  = (const float*)d_in[2];
  const float* in_b  = (const float*)d_in[3];
  const float* out_v = (const float*)d_in[4];
  const float* out_g = (const float*)d_in[5];
  const float* out_b = (const float*)d_in[6];

  float* out     = (float*)d_out;                    // 16*512*4096
  float* out_idx = out + (size_t)B_*D_*T_;           // 65536 (indices as f32)
  float* aux     = out_idx + NTOK;                   // 1

  float* wsf = (float*)d_ws;
  int*   cnt = (int*)(wsf + WS_CNT);

  prep_wt<<<dim3(12), dim3(256), 0, stream>>>(
      in_v, in_g, out_v, out_g, out_b,
      wsf + WS_WT, wsf + WS_WNP, cnt);
  lfq_fused<<<dim3(NBLK_A), dim3(256), 0, stream>>>(
      x, in_b, wsf + WS_WT, wsf + WS_WNP,
      out, out_idx,
      wsf + WS_PARTH, wsf + WS_PARTC, wsf + WS_HIST);
  hist_final<<<dim3(32), dim3(256), 0, stream>>>(
      wsf + WS_HIST, wsf + WS_PARTH, wsf + WS_PARTC,
      wsf + WS_HMID, cnt, aux);
}

// Round 11
// 64.191 us; speedup vs baseline: 1.1202x; 1.1202x over previous
//
#include <hip/hip_runtime.h>
#include <math.h>

#define B_   16
#define D_   512
#define T_   4096
#define CD   10
#define CS   1024
#define NTOK (B_*T_)              // 65536
#define TPB_A 128                 // tokens per block, fused kernel
#define NBLK_A (NTOK/TPB_A)       // 512

typedef float f32x2 __attribute__((ext_vector_type(2)));
typedef float f32x4 __attribute__((ext_vector_type(4)));

// ws layout (float offsets)
#define WS_WT     0               // 5120  (w_t[D][d], transposed, normalized)
#define WS_PARTH  5120            // 1024
#define WS_PARTC  6144            // 1024
#define WS_CNT    7168            // 1 (int ticket counter)
#define WS_HIST   7424            // 512*1024 = 524288
#define WS_HMID   531712          // 32*1024

// --------------------------------------------- prep: transposed w_in
// 10 blocks, block d: norm over in_v[d,:], write w_t[D*10+d].
// f32/f64 arithmetic order identical to the validated R3/R5/R7/R9 version.
__global__ __launch_bounds__(256) void prep_wt(
    const float* __restrict__ in_v, const float* __restrict__ in_g,
    float* __restrict__ w_t, int* __restrict__ counter)
{
  __shared__ double pn[16];
  __shared__ float nrm_s;
  const int d   = blockIdx.x;
  const int tid = threadIdx.x;
  if (d == 0 && tid == 0) *counter = 0;     // reset cooperative ticket
  if (tid < 16) {
    double s = 0.0;
    const float* vp = in_v + d*D_ + tid*32;
    #pragma unroll
    for (int k = 0; k < 32; ++k) { double v = (double)vp[k]; s += v*v; }
    pn[tid] = s;
  }
  __syncthreads();
  if (tid == 0) {
    double s = 0.0;
    #pragma unroll
    for (int j = 0; j < 16; ++j) s += pn[j];
    nrm_s = (float)sqrt(s);
  }
  __syncthreads();
  const float g = in_g[d], nrm = nrm_s;
  for (int D = tid; D < D_; D += 256)
    w_t[D*CD + d] = g * in_v[d*D_ + D] / nrm;
}

// ------------------------------------- fused: in-proj + stats + out-proj
// Phases A/B identical to validated R9. Phase C: packed wnb[D][12] LDS
// (3x ds_read_b128/row) + per-token sign vectors + fmaf chain (arithmetic
// bit-identical: base=ob, ascending d, one add rounding per step).
__global__ __launch_bounds__(256) void lfq_fused(
    const float* __restrict__ x, const float* __restrict__ in_b,
    const float* __restrict__ w_t,
    const float* __restrict__ out_v, const float* __restrict__ out_g,
    const float* __restrict__ out_b,
    float* __restrict__ out, float* __restrict__ out_idx,
    float* __restrict__ partH, float* __restrict__ partC,
    float* __restrict__ hist_part)
{
  __shared__ float  hist[CS];            // 4 KB
  __shared__ int    sidx[TPB_A];         // 512 B
  __shared__ double red[4*TPB_A*CD];     // 40 KB
  __shared__ float  wnb[D_*12];          // 24.5 KB (10 wn + ob + pad per D)

  const int tid  = threadIdx.x;
  const int blk  = blockIdx.x;
  const int b    = blk >> 5;
  const int t0   = (blk & 31) * TPB_A;
  const int wave = __builtin_amdgcn_readfirstlane(tid >> 6);
  const int lane = tid & 63;

  for (int i = tid; i < CS; i += 256) hist[i] = 0.f;

  // phase A: f64 in-proj. wave = 128-D slice, lane = 2 tokens (float2).
  // weight addresses wave-uniform -> scalar (SMEM) loads.
  double acc[2*CD];
  #pragma unroll
  for (int i = 0; i < 2*CD; ++i) acc[i] = 0.0;
  const float* xb = x + ((size_t)b * D_ + wave * 128) * T_ + t0 + 2*lane;
  const float* wp = w_t + (size_t)wave * 128 * CD;
  #pragma unroll 8
  for (int Di = 0; Di < 128; ++Di) {
    f32x2 xv = *(const f32x2*)(xb + (size_t)Di * T_);
    double x0 = (double)xv.x, x1 = (double)xv.y;
    const f32x2* w2 = (const f32x2*)(wp + Di * CD);
    #pragma unroll
    for (int i = 0; i < 5; ++i) {
      f32x2 w = w2[i];
      acc[4*i+0] += (double)w.x * x0;
      acc[4*i+1] += (double)w.x * x1;
      acc[4*i+2] += (double)w.y * x0;
      acc[4*i+3] += (double)w.y * x1;
    }
  }
  #pragma unroll
  for (int d = 0; d < CD; ++d) {
    red[((size_t)wave*TPB_A + 2*lane + 0)*CD + d] = acc[2*d+0];
    red[((size_t)wave*TPB_A + 2*lane + 1)*CD + d] = acc[2*d+1];
  }
  __syncthreads();

  // phase B: waves 0,1 -> quantize / entropy / histogram;
  //          waves 2,3 -> stage packed wnb into LDS (validated op order)
  if (wave < 2) {
    const int ti = wave*64 + lane;
    float Hs = 0.f, C = 0.f;
    int   idx = 0;
    int   k = 0; int pos[CD]; float ms[CD];
    #pragma unroll
    for (int d = 0; d < CD; ++d) {
      double o = red[(size_t)(0*TPB_A + ti)*CD + d]
               + red[(size_t)(1*TPB_A + ti)*CD + d]
               + red[(size_t)(2*TPB_A + ti)*CD + d]
               + red[(size_t)(3*TPB_A + ti)*CD + d]
               + (double)in_b[d];
      float v = (float)o;
      int bit = (v > 0.f);
      idx |= bit << (9 - d);
      float c = v - (bit ? 1.f : -1.f);
      C += c * c;
      float e = __expf(-400.f * fabsf(v));   // exp(-|delta logit|)
      if (e > 1e-9f) { ms[k] = e / (1.f + e); pos[k] = 9 - d; ++k; }
    }
    int nc = 1 << k;
    for (int c = 0; c < nc; ++c) {
      float p = 1.f; int bin = idx;
      for (int i = 0; i < k; ++i) {
        if ((c >> i) & 1) { p *= ms[i]; bin ^= (1 << pos[i]); }
        else              { p *= (1.f - ms[i]); }
      }
      Hs -= p * __logf(fmaxf(p, 1e-5f));
      atomicAdd(&hist[bin], p);
    }
    out_idx[b * T_ + t0 + ti] = (float)idx;
    sidx[ti] = idx;
    #pragma unroll
    for (int off = 32; off > 0; off >>= 1) {
      Hs += __shfl_down(Hs, off, 64);
      C  += __shfl_down(C,  off, 64);
    }
    if (lane == 0) { partH[blk*2 + wave] = Hs; partC[blk*2 + wave] = C; }
  } else {
    const int local = tid - 128;           // 0..127, 4 D-rows each
    #pragma unroll
    for (int r = 0; r < 4; ++r) {
      const int D = local*4 + r;
      const float* vr = out_v + D*CD;
      float vv[CD];
      float s2 = 0.f;
      #pragma unroll
      for (int d = 0; d < CD; ++d) { vv[d] = vr[d]; s2 += vv[d]*vv[d]; }
      const float sc = out_g[D] / sqrtf(s2);
      #pragma unroll
      for (int d = 0; d < CD; ++d) wnb[D*12 + d] = vv[d] * sc;
      wnb[D*12 + 10] = out_b[D];
      wnb[D*12 + 11] = 0.f;
    }
  }
  __syncthreads();

  for (int i = tid; i < CS; i += 256) hist_part[(size_t)blk*CS + i] = hist[i];

  // phase C: direct out-projection. Thread owns 4 fixed tokens, walks 64 D.
  // sg precomputed once; inner = fmaf chain (bit-identical to +=(+-w)).
  const int t4 = (tid & 31) * 4;
  const int c0 = sidx[t4+0], c1 = sidx[t4+1], c2 = sidx[t4+2], c3 = sidx[t4+3];
  float sg0[CD], sg1[CD], sg2[CD], sg3[CD];
  #pragma unroll
  for (int d = 0; d < CD; ++d) {
    const int sh = 9 - d;
    sg0[d] = ((c0 >> sh) & 1) ? 1.f : -1.f;
    sg1[d] = ((c1 >> sh) & 1) ? 1.f : -1.f;
    sg2[d] = ((c2 >> sh) & 1) ? 1.f : -1.f;
    sg3[d] = ((c3 >> sh) & 1) ? 1.f : -1.f;
  }
  const int Dbase = tid >> 5;
  float* op = out + ((size_t)b * D_) * T_ + t0 + t4;
  #pragma unroll 4
  for (int it = 0; it < 64; ++it) {
    const int D = Dbase + it*8;
    const f32x4* w4 = (const f32x4*)(wnb + D*12);
    const f32x4 wa = w4[0];            // d 0..3
    const f32x4 wb = w4[1];            // d 4..7
    const f32x4 wc = w4[2];            // d 8,9, ob, pad
    const float base = wc.z;           // ob
    float s0 = base, s1 = base, s2 = base, s3 = base;
    #define STEP(W, D_IDX) \
      s0 = fmaf(W, sg0[D_IDX], s0); s1 = fmaf(W, sg1[D_IDX], s1); \
      s2 = fmaf(W, sg2[D_IDX], s2); s3 = fmaf(W, sg3[D_IDX], s3);
    STEP(wa.x, 0) STEP(wa.y, 1) STEP(wa.z, 2) STEP(wa.w, 3)
    STEP(wb.x, 4) STEP(wb.y, 5) STEP(wb.z, 6) STEP(wb.w, 7)
    STEP(wc.x, 8) STEP(wc.y, 9)
    #undef STEP
    f32x4 o; o.x = s0; o.y = s1; o.z = s2; o.w = s3;
    __builtin_nontemporal_store(o, (f32x4*)(op + (size_t)D * T_));
  }
}

// --------------------------- tail: hist reduce + finalize (cooperative)
// Validated in R6/R7/R9.
__global__ __launch_bounds__(256) void hist_final(
    const float* __restrict__ hist_part, const float* __restrict__ partH,
    const float* __restrict__ partC, float* __restrict__ hmid,
    int* __restrict__ counter, float* __restrict__ aux_out)
{
  const int r   = blockIdx.x;          // 0..31
  const int tid = threadIdx.x;
  #pragma unroll
  for (int q = 0; q < 4; ++q) {
    const int bin = q*256 + tid;
    float s = 0.f;
    for (int m = 0; m < 16; ++m)
      s += hist_part[(size_t)(r*16 + m)*CS + bin];
    hmid[r*CS + bin] = s;
  }
  __threadfence();
  __shared__ int ticket_s;
  if (tid == 0) ticket_s = atomicAdd(counter, 1);
  __syncthreads();
  if (ticket_s != 31) return;          // not the last block
  __threadfence();                     // acquire: others' hmid now visible

  float ce = 0.f, h = 0.f, cm = 0.f;
  #pragma unroll
  for (int q = 0; q < 4; ++q) {
    const int bin = q*256 + tid;
    float s = 0.f;
    for (int rr = 0; rr < 32; ++rr) s += hmid[rr*CS + bin];
    float ap = s * (1.f/65536.f);
    ce += -ap * __logf(fmaxf(ap, 1e-5f));
  }
  for (int i = tid; i < 1024; i += 256) { h += partH[i]; cm += partC[i]; }
  __shared__ float rb[3][256];
  rb[0][tid] = ce; rb[1][tid] = h; rb[2][tid] = cm;
  __syncthreads();
  for (int s = 128; s > 0; s >>= 1) {
    if (tid < s) {
      rb[0][tid] += rb[0][tid+s];
      rb[1][tid] += rb[1][tid+s];
      rb[2][tid] += rb[2][tid+s];
    }
    __syncthreads();
  }
  if (tid == 0) {
    float psH    = rb[1][0] * (1.f/65536.f);
    float commit = rb[2][0] * (1.f/655360.f);
    aux_out[0] = psH - rb[0][0] + commit;
  }
}

// ---------------------------------------------------------------- launch
extern "C" void kernel_launch(void* const* d_in, const int* in_sizes, int n_in,
                              void* d_out, int out_size, void* d_ws, size_t ws_size,
                              hipStream_t stream) {
  const float* x     = (const float*)d_in[0];
  const float* in_v  = (const float*)d_in[1];
  const float* in_g  = (const float*)d_in[2];
  const float* in_b  = (const float*)d_in[3];
  const float* out_v = (const float*)d_in[4];
  const float* out_g = (const float*)d_in[5];
  const float* out_b = (const float*)d_in[6];

  float* out     = (float*)d_out;                    // 16*512*4096
  float* out_idx = out + (size_t)B_*D_*T_;           // 65536 (indices as f32)
  float* aux     = out_idx + NTOK;                   // 1

  float* wsf = (float*)d_ws;
  int*   cnt = (int*)(wsf + WS_CNT);

  prep_wt<<<dim3(CD), dim3(256), 0, stream>>>(in_v, in_g, wsf + WS_WT, cnt);
  lfq_fused<<<dim3(NBLK_A), dim3(256), 0, stream>>>(
      x, in_b, wsf + WS_WT, out_v, out_g, out_b,
      out, out_idx,
      wsf + WS_PARTH, wsf + WS_PARTC, wsf + WS_HIST);
  hist_final<<<dim3(32), dim3(256), 0, stream>>>(
      wsf + WS_HIST, wsf + WS_PARTH, wsf + WS_PARTC,
      wsf + WS_HMID, cnt, aux);
}